// Round 13
// baseline (590.502 us; speedup 1.0000x reference)
//
#include <hip/hip_runtime.h>
#include <hip/hip_bf16.h>

#define B_   64
#define S_   2048
#define H_   256
#define H3_  768
#define K_   512            // 2H (static+dynamic)
#define MT   64             // M tile rows per block
#define RST  136            // LDS row stride in SHORTS (272 B): uniform bank spread

typedef __attribute__((ext_vector_type(8))) short  bf16x8;
typedef __attribute__((ext_vector_type(4))) float  f32x4;

__device__ __forceinline__ uint pkbf2(float a, float b) {
    float2 f = make_float2(a, b);
    __hip_bfloat162 h = __float22bfloat162_rn(f);   // v_cvt_pk_bf16_f32
    return *reinterpret_cast<uint*>(&h);
}

// ---------------- kernel 1: pack W[:, 0:512] to bf16 in FRAGMENT order.
// Layout: [ot(48)][ks(16)][lane(64)][j(8)]
//   o = ot*16 + (lane&15), k = ks*32 + (lane>>4)*8 + j
__global__ void pack_w(const float* __restrict__ W, short* __restrict__ wpk) {
    int t = blockIdx.x * 256 + threadIdx.x;       // over 48*16*64
    if (t >= 48 * 16 * 64) return;
    int lane = t & 63;
    int ks   = (t >> 6) & 15;
    int ot   = t >> 10;
    int o  = ot * 16 + (lane & 15);
    int kb = ks * 32 + (lane >> 4) * 8;
    const float* src = W + (size_t)o * H3_ + kb;
    float4 a = ((const float4*)src)[0];
    float4 b = ((const float4*)src)[1];
    uint4 pk;
    pk.x = pkbf2(a.x, a.y);
    pk.y = pkbf2(a.z, a.w);
    pk.z = pkbf2(b.x, b.y);
    pk.w = pkbf2(b.z, b.w);
    *(uint4*)(wpk + (size_t)t * 8) = pk;
}

// ---------------- kernel 2: bias[b,o] = sum_k W[o,512+k]*dec[b,k]
__global__ void bias_k(const float* __restrict__ W, const float* __restrict__ dec,
                       float* __restrict__ bias) {
    int idx = blockIdx.x * 256 + threadIdx.x;     // over 64*768
    if (idx >= B_ * H3_) return;
    int b = idx / H3_;
    int o = idx - b * H3_;
    const float4* wr = (const float4*)(W + (size_t)o * H3_ + 2 * H_);
    const float4* dv = (const float4*)(dec + (size_t)b * H_);
    float s = 0.f;
#pragma unroll 8
    for (int k = 0; k < H_ / 4; ++k) {
        float4 a = wr[k], d = dv[k];
        s += a.x * d.x + a.y * d.y + a.z * d.z + a.w * d.w;
    }
    bias[idx] = s;
}

// ---------------- kernel 3: fused score GEMM, BK=128 double-buffered LDS.
// Block (rt, g): 64 rows x 192 cols (g in 0..3). 256 thr, 4 waves x 3 o-tiles.
// acc persists across 4 K-chunks; partial col-sums go to part[g][pos].
// part[pos] = sum_{o in group} (-2 v[o]) * rcp(exp2(C1*h[pos,o]) + 1)
// (global constant vsum dropped: softmax is shift-invariant.)
__global__ __launch_bounds__(256, 4)
void score_k(const float* __restrict__ stat, const float* __restrict__ dyn,
             const short* __restrict__ wpk, const float* __restrict__ bias,
             const float* __restrict__ v, float* __restrict__ part) {
    __shared__ short aT[2][MT * RST];        // 2 x 17408 B
    __shared__ float sred[4][MT];            // 1 KB

    const int tid  = threadIdx.x;
    const int bid  = blockIdx.x;
    const int rt   = bid >> 2;               // row-tile 0..2047
    const int g    = bid & 3;                // col-group 0..3
    const int pos0 = rt * MT;
    const int bidx = pos0 >> 11;             // batch; tile never crosses b

    const int wave = tid >> 6;
    const int lane = tid & 63;
    const int lr   = lane & 15;              // A row-in-16 / C col-in-16
    const int lg   = lane >> 4;              // k-subgroup

    const float C1 = 2.8853900817779268f;    // 2*log2(e)

    // epilogue constants for this wave's 3 o-tiles
    float bv[3], vv2[3];
#pragma unroll
    for (int ni = 0; ni < 3; ++ni) {
        int o = (g * 12 + wave * 3 + ni) * 16 + lr;
        bv[ni]  = bias[bidx * H3_ + o];
        vv2[ni] = -2.0f * v[o];
    }

    // ---- staging: chunk = 64 rows x 128 k (f32).  thread: row=tid>>2, q=tid&3,
    // covers k = q*32..q*32+31 (8 float4 loads -> 4x 16B LDS writes).
    const int srow = tid >> 2;
    const int q    = tid & 3;
    float4 f0[4], f1[4];
    auto stage_load = [&](int ch) {
        const float* base = (ch < 2)
            ? (stat + (size_t)(pos0 + srow) * H_ + ch * 128 + q * 32)
            : (dyn  + (size_t)(pos0 + srow) * H_ + (ch - 2) * 128 + q * 32);
#pragma unroll
        for (int u = 0; u < 4; ++u) {
            f0[u] = ((const float4*)base)[u * 2];
            f1[u] = ((const float4*)base)[u * 2 + 1];
        }
    };
    auto stage_write = [&](int bufi) {
        short* dst = aT[bufi] + srow * RST + q * 32;
#pragma unroll
        for (int u = 0; u < 4; ++u) {
            uint4 pk;
            pk.x = pkbf2(f0[u].x, f0[u].y);
            pk.y = pkbf2(f0[u].z, f0[u].w);
            pk.z = pkbf2(f1[u].x, f1[u].y);
            pk.w = pkbf2(f1[u].z, f1[u].w);
            *(uint4*)(dst + u * 8) = pk;
        }
    };

    f32x4 acc[4][3];                          // [mi][ni], init = bias
#pragma unroll
    for (int mi = 0; mi < 4; ++mi)
#pragma unroll
        for (int ni = 0; ni < 3; ++ni) {
            f32x4 a = {bv[ni], bv[ni], bv[ni], bv[ni]};
            acc[mi][ni] = a;
        }

    const short* wbase = wpk + (size_t)(g * 12 + wave * 3) * 8192 + lane * 8;

    // prologue
    stage_load(0);
    stage_write(0);
    __syncthreads();

    // K-loop: 4 chunks of BK=128 (4 ks-steps each)
#pragma unroll 1
    for (int ch = 0; ch < 4; ++ch) {
        if (ch < 3) stage_load(ch + 1);       // issue early; hides under MFMA
        const short* abuf = aT[ch & 1] + lr * RST + lg * 8;
#pragma unroll
        for (int ksl = 0; ksl < 4; ++ksl) {
            const int ks = ch * 4 + ksl;
            bf16x8 bfr[3];
#pragma unroll
            for (int ni = 0; ni < 3; ++ni)
                bfr[ni] = *(const bf16x8*)(wbase + ni * 8192 + ks * 512);
            bf16x8 afr[4];
#pragma unroll
            for (int mi = 0; mi < 4; ++mi)
                afr[mi] = *(const bf16x8*)(abuf + mi * 16 * RST + ksl * 32);
            __builtin_amdgcn_s_setprio(1);
#pragma unroll
            for (int mi = 0; mi < 4; ++mi)
#pragma unroll
                for (int ni = 0; ni < 3; ++ni)
                    acc[mi][ni] = __builtin_amdgcn_mfma_f32_16x16x32_bf16(
                        afr[mi], bfr[ni], acc[mi][ni], 0, 0, 0);
            __builtin_amdgcn_s_setprio(0);
        }
        if (ch < 3) stage_write((ch + 1) & 1);
        __syncthreads();
    }

    // epilogue: sacc[mi][j] = sum_ni (-2 v)*rcp(exp2(C1*h)+1)
    float sacc[4][4];
#pragma unroll
    for (int mi = 0; mi < 4; ++mi)
#pragma unroll
        for (int j = 0; j < 4; ++j) sacc[mi][j] = 0.f;
#pragma unroll
    for (int ni = 0; ni < 3; ++ni)
#pragma unroll
        for (int mi = 0; mi < 4; ++mi)
#pragma unroll
            for (int j = 0; j < 4; ++j) {
                float e = __builtin_amdgcn_exp2f(acc[mi][ni][j] * C1);
                float r = __builtin_amdgcn_rcpf(e + 1.0f);
                sacc[mi][j] = fmaf(vv2[ni], r, sacc[mi][j]);
            }

    // reduce over the 16 column-lanes; rows live at mi*16 + lg*4 + j
#pragma unroll
    for (int mi = 0; mi < 4; ++mi)
#pragma unroll
        for (int j = 0; j < 4; ++j) {
            float x = sacc[mi][j];
            x += __shfl_xor(x, 1);
            x += __shfl_xor(x, 2);
            x += __shfl_xor(x, 4);
            x += __shfl_xor(x, 8);
            sacc[mi][j] = x;
        }
    if (lr == 0) {
#pragma unroll
        for (int mi = 0; mi < 4; ++mi)
#pragma unroll
            for (int j = 0; j < 4; ++j)
                sred[wave][mi * 16 + lg * 4 + j] = sacc[mi][j];
    }
    __syncthreads();
    if (tid < MT) {
        float s = sred[0][tid] + sred[1][tid] + sred[2][tid] + sred[3][tid];
        part[(size_t)g * (B_ * S_) + pos0 + tid] = s;
    }
}

// ---------------- kernel 4: softmax over S=2048 per b; sums 4 col-group partials
__global__ void softmax_k(const float* __restrict__ part, float* __restrict__ out) {
    const int b = blockIdx.x;
    const int tid  = threadIdx.x;          // 256
    const int wave = tid >> 6;
    const int lane = tid & 63;
    const int base = b * S_;

    float vals[8];
    float m = -1e30f;
#pragma unroll
    for (int i = 0; i < 8; ++i) {
        int idx = base + tid + i * 256;
        vals[i] = part[idx] + part[idx + B_ * S_] + part[idx + 2 * B_ * S_]
                + part[idx + 3 * B_ * S_];
        m = fmaxf(m, vals[i]);
    }
#pragma unroll
    for (int off = 32; off >= 1; off >>= 1) m = fmaxf(m, __shfl_xor(m, off));
    __shared__ float redm[4];
    __shared__ float reds[4];
    if (lane == 0) redm[wave] = m;
    __syncthreads();
    m = fmaxf(fmaxf(redm[0], redm[1]), fmaxf(redm[2], redm[3]));

    float s = 0.f;
#pragma unroll
    for (int i = 0; i < 8; ++i) {
        vals[i] = __expf(vals[i] - m);
        s += vals[i];
    }
#pragma unroll
    for (int off = 32; off >= 1; off >>= 1) s += __shfl_xor(s, off);
    if (lane == 0) reds[wave] = s;
    __syncthreads();
    s = reds[0] + reds[1] + reds[2] + reds[3];
    float inv = 1.0f / s;
    float* row = out + (size_t)base;
#pragma unroll
    for (int i = 0; i < 8; ++i) row[tid + i * 256] = vals[i] * inv;
}

extern "C" void kernel_launch(void* const* d_in, const int* in_sizes, int n_in,
                              void* d_out, int out_size, void* d_ws, size_t ws_size,
                              hipStream_t stream) {
    const float* stat = (const float*)d_in[0];   // [64,2048,256]
    const float* dyn  = (const float*)d_in[1];   // [64,2048,256]
    const float* dec  = (const float*)d_in[2];   // [64,256]
    const float* v    = (const float*)d_in[3];   // [1,768]
    const float* W    = (const float*)d_in[4];   // [768,768]
    float* out = (float*)d_out;                  // [64,2048]

    short* wpk  = (short*)d_ws;                                 // 786432 B
    float* bias = (float*)((char*)d_ws + (size_t)H3_ * K_ * 2); // 196608 B
    float* part = bias + B_ * H3_;                              // 4*131072*4 B

    pack_w <<<(48 * 16 * 64 + 255) / 256, 256, 0, stream>>>(W, wpk);
    bias_k <<<(B_ * H3_ + 255) / 256, 256, 0, stream>>>(W, dec, bias);
    score_k<<<(B_ * S_ / MT) * 4, 256, 0, stream>>>(stat, dyn, wpk, bias, v, part);
    softmax_k<<<B_, 256, 0, stream>>>(part, out);
}

// Round 14
// 152.563 us; speedup vs baseline: 3.8705x; 3.8705x over previous
//
#include <hip/hip_runtime.h>
#include <hip/hip_bf16.h>

#define B_   64
#define S_   2048
#define H_   256
#define H3_  768
#define MT   128            // M tile rows per block
#define RSH  528            // LDS row stride bytes for K=256 half (33 x 16B)
#define HALF (MT * RSH)     // 67584 B per K-half

typedef __attribute__((ext_vector_type(8))) short  bf16x8;
typedef __attribute__((ext_vector_type(4))) float  f32x4;

__device__ __forceinline__ uint pkbf2(float a, float b) {
    float2 f = make_float2(a, b);
    __hip_bfloat162 h = __float22bfloat162_rn(f);   // v_cvt_pk_bf16_f32
    return *reinterpret_cast<uint*>(&h);
}

// ---------------- kernel 1: pack W[:, 0:512] to bf16 in FRAGMENT order.
// Layout: [ot(48)][ks(16)][lane(64)][j(8)]
//   o = ot*16 + (lane&15), k = ks*32 + (lane>>4)*8 + j
__global__ void pack_w(const float* __restrict__ W, short* __restrict__ wpk) {
    int t = blockIdx.x * 256 + threadIdx.x;       // over 48*16*64
    if (t >= 48 * 16 * 64) return;
    int lane = t & 63;
    int ks   = (t >> 6) & 15;
    int ot   = t >> 10;
    int o  = ot * 16 + (lane & 15);
    int kb = ks * 32 + (lane >> 4) * 8;
    const float* src = W + (size_t)o * H3_ + kb;
    float4 a = ((const float4*)src)[0];
    float4 b = ((const float4*)src)[1];
    uint4 pk;
    pk.x = pkbf2(a.x, a.y);
    pk.y = pkbf2(a.z, a.w);
    pk.z = pkbf2(b.x, b.y);
    pk.w = pkbf2(b.z, b.w);
    *(uint4*)(wpk + (size_t)t * 8) = pk;
}

// ---------------- kernel 2: bias[b,o] = sum_k W[o,512+k]*dec[b,k]
__global__ void bias_k(const float* __restrict__ W, const float* __restrict__ dec,
                       float* __restrict__ bias) {
    int idx = blockIdx.x * 256 + threadIdx.x;     // over 64*768
    if (idx >= B_ * H3_) return;
    int b = idx / H3_;
    int o = idx - b * H3_;
    const float4* wr = (const float4*)(W + (size_t)o * H3_ + 2 * H_);
    const float4* dv = (const float4*)(dec + (size_t)b * H_);
    float s = 0.f;
#pragma unroll 8
    for (int k = 0; k < H_ / 4; ++k) {
        float4 a = wr[k], d = dv[k];
        s += a.x * d.x + a.y * d.y + a.z * d.z + a.w * d.w;
    }
    bias[idx] = s;
}

// ---------------- kernel 3: fused score GEMM, MT=128, 8 waves, 1 block/CU.
// LDS: two K=256 halves (half0=static cols, half1=dynamic cols), 135 KB.
// Half1 loads issue under half0 compute; pass1 runs barrier-free.
// Wave covers o-tiles ot = wave*6 + p*3 + ni (p=0..1, ni=0..2).
// scores[pos] = sum_o (-2 v[o]) * rcp(exp2(C1*h[pos,o]) + 1)   (+const dropped)
__global__ __launch_bounds__(512, 1)
void score_k(const float* __restrict__ stat, const float* __restrict__ dyn,
             const short* __restrict__ wpk, const float* __restrict__ bias,
             const float* __restrict__ v, float* __restrict__ scores) {
    __shared__ char  aT[2 * HALF];           // 135168 B
    __shared__ float sred[8][MT];            // 4 KB

    const int tid  = threadIdx.x;
    const int pos0 = blockIdx.x * MT;
    const int bidx = pos0 >> 11;             // 16 tiles per batch; never crosses

    const int wave = tid >> 6;
    const int lane = tid & 63;
    const int lr   = lane & 15;              // A row-in-16 / C col-in-16
    const int lg   = lane >> 4;              // k-subgroup

    const float C1 = 2.8853900817779268f;    // 2*log2(e)
    const short* wbase = wpk + (size_t)lane * 8;

    // ---- staging: half h (128 rows x 256 k fp32 = 128 KB). 4096 units of
    // 8 floats; thread does 8 units in 2 batches of 4 (8 dwordx4 in flight).
    float4 f0[4], f1[4];
    auto loadb = [&](int h, int bat) {
        const float* srcb = (h == 0) ? stat : dyn;
#pragma unroll
        for (int i = 0; i < 4; ++i) {
            int lin = (bat * 4 + i) * 512 + tid;
            int row = lin >> 5;              // 32 units per row
            int un  = lin & 31;
            const float4* p = (const float4*)(srcb + (size_t)(pos0 + row) * H_ + un * 8);
            f0[i] = p[0];
            f1[i] = p[1];
        }
    };
    auto writeb = [&](int h, int bat) {
#pragma unroll
        for (int i = 0; i < 4; ++i) {
            int lin = (bat * 4 + i) * 512 + tid;
            int row = lin >> 5;
            int un  = lin & 31;
            uint4 pk;
            pk.x = pkbf2(f0[i].x, f0[i].y);
            pk.y = pkbf2(f0[i].z, f0[i].w);
            pk.z = pkbf2(f1[i].x, f1[i].y);
            pk.w = pkbf2(f1[i].z, f1[i].w);
            *(uint4*)(aT + h * HALF + row * RSH + un * 16) = pk;
        }
    };

    // prologue: stage half 0 (static)
    loadb(0, 0); writeb(0, 0);
    loadb(0, 1); writeb(0, 1);
    __syncthreads();

    float sacc[8][4];
#pragma unroll
    for (int mi = 0; mi < 8; ++mi)
#pragma unroll
        for (int j = 0; j < 4; ++j) sacc[mi][j] = 0.f;

    const char* abase0 = aT + lr * RSH + lg * 16;

    // one ks step: bfr(lookahead-fed) + 8 afr + 24 MFMA
    f32x4 acc[8][3];
    bf16x8 bcur[3];
    auto ksstep = [&](const short* wp, int ks) {
        const int h = ks >> 3, ksl = ks & 7;
        const int ksn = (ks + 1) & 15;
        bf16x8 bnx[3];
#pragma unroll
        for (int ni = 0; ni < 3; ++ni)
            bnx[ni] = *(const bf16x8*)(wp + ni * 8192 + ksn * 512);
        const char* ab = abase0 + h * HALF + ksl * 64;
        bf16x8 afr[8];
#pragma unroll
        for (int mi = 0; mi < 8; ++mi)
            afr[mi] = *(const bf16x8*)(ab + mi * (16 * RSH));
        __builtin_amdgcn_s_setprio(1);
#pragma unroll
        for (int mi = 0; mi < 8; ++mi)
#pragma unroll
            for (int ni = 0; ni < 3; ++ni)
                acc[mi][ni] = __builtin_amdgcn_mfma_f32_16x16x32_bf16(
                    afr[mi], bcur[ni], acc[mi][ni], 0, 0, 0);
        __builtin_amdgcn_s_setprio(0);
#pragma unroll
        for (int ni = 0; ni < 3; ++ni) bcur[ni] = bnx[ni];
    };

    const short* wp0 = wbase + (size_t)(wave * 6) * 8192;
    const short* wp1 = wbase + (size_t)(wave * 6 + 3) * 8192;

    // ================= pass 0 (with half-1 staging interleaved)
    {
        float bv[3], vv2[3];
#pragma unroll
        for (int ni = 0; ni < 3; ++ni) {
            int o = (wave * 6 + ni) * 16 + lr;
            bv[ni]  = bias[bidx * H3_ + o];
            vv2[ni] = -2.0f * v[o];
        }
#pragma unroll
        for (int mi = 0; mi < 8; ++mi)
#pragma unroll
            for (int ni = 0; ni < 3; ++ni) {
                f32x4 a = {bv[ni], bv[ni], bv[ni], bv[ni]};
                acc[mi][ni] = a;
            }
#pragma unroll
        for (int ni = 0; ni < 3; ++ni)
            bcur[ni] = *(const bf16x8*)(wp0 + ni * 8192);

        loadb(1, 0);                          // half-1 batch 0 in flight
#pragma unroll 4
        for (int ks = 0; ks < 4; ++ks) ksstep(wp0, ks);
        writeb(1, 0);
        loadb(1, 1);                          // half-1 batch 1 in flight
#pragma unroll 4
        for (int ks = 4; ks < 8; ++ks) ksstep(wp0, ks);
        writeb(1, 1);
        __syncthreads();                      // half 1 ready
#pragma unroll 4
        for (int ks = 8; ks < 16; ++ks) ksstep(wp0, ks);

        // preload pass-1 ks0 B; epilogue covers latency
#pragma unroll
        for (int ni = 0; ni < 3; ++ni)
            bcur[ni] = *(const bf16x8*)(wp1 + ni * 8192);

#pragma unroll
        for (int ni = 0; ni < 3; ++ni)
#pragma unroll
            for (int mi = 0; mi < 8; ++mi)
#pragma unroll
                for (int j = 0; j < 4; ++j) {
                    float e = __builtin_amdgcn_exp2f(acc[mi][ni][j] * C1);
                    float r = __builtin_amdgcn_rcpf(e + 1.0f);
                    sacc[mi][j] = fmaf(vv2[ni], r, sacc[mi][j]);
                }
    }

    // ================= pass 1 (both halves resident; no barriers)
    {
        float bv[3], vv2[3];
#pragma unroll
        for (int ni = 0; ni < 3; ++ni) {
            int o = (wave * 6 + 3 + ni) * 16 + lr;
            bv[ni]  = bias[bidx * H3_ + o];
            vv2[ni] = -2.0f * v[o];
        }
#pragma unroll
        for (int mi = 0; mi < 8; ++mi)
#pragma unroll
            for (int ni = 0; ni < 3; ++ni) {
                f32x4 a = {bv[ni], bv[ni], bv[ni], bv[ni]};
                acc[mi][ni] = a;
            }
#pragma unroll 4
        for (int ks = 0; ks < 16; ++ks) ksstep(wp1, ks);

#pragma unroll
        for (int ni = 0; ni < 3; ++ni)
#pragma unroll
            for (int mi = 0; mi < 8; ++mi)
#pragma unroll
                for (int j = 0; j < 4; ++j) {
                    float e = __builtin_amdgcn_exp2f(acc[mi][ni][j] * C1);
                    float r = __builtin_amdgcn_rcpf(e + 1.0f);
                    sacc[mi][j] = fmaf(vv2[ni], r, sacc[mi][j]);
                }
    }

    // reduce over the 16 column-lanes; rows live at mi*16 + lg*4 + j
#pragma unroll
    for (int mi = 0; mi < 8; ++mi)
#pragma unroll
        for (int j = 0; j < 4; ++j) {
            float x = sacc[mi][j];
            x += __shfl_xor(x, 1);
            x += __shfl_xor(x, 2);
            x += __shfl_xor(x, 4);
            x += __shfl_xor(x, 8);
            sacc[mi][j] = x;
        }
    if (lr == 0) {
#pragma unroll
        for (int mi = 0; mi < 8; ++mi)
#pragma unroll
            for (int j = 0; j < 4; ++j)
                sred[wave][mi * 16 + lg * 4 + j] = sacc[mi][j];
    }
    __syncthreads();
    if (tid < MT) {
        float s = 0.f;
#pragma unroll
        for (int w = 0; w < 8; ++w) s += sred[w][tid];
        scores[pos0 + tid] = s;
    }
}

// ---------------- kernel 4: softmax over S=2048 per b, in place on d_out
__global__ void softmax_k(float* __restrict__ out) {
    const int b = blockIdx.x;
    float* row = out + (size_t)b * S_;
    const int tid  = threadIdx.x;          // 256
    const int wave = tid >> 6;
    const int lane = tid & 63;

    float vals[8];
    float m = -1e30f;
#pragma unroll
    for (int i = 0; i < 8; ++i) {
        vals[i] = row[tid + i * 256];
        m = fmaxf(m, vals[i]);
    }
#pragma unroll
    for (int off = 32; off >= 1; off >>= 1) m = fmaxf(m, __shfl_xor(m, off));
    __shared__ float redm[4];
    __shared__ float reds[4];
    if (lane == 0) redm[wave] = m;
    __syncthreads();
    m = fmaxf(fmaxf(redm[0], redm[1]), fmaxf(redm[2], redm[3]));

    float s = 0.f;
#pragma unroll
    for (int i = 0; i < 8; ++i) {
        vals[i] = __expf(vals[i] - m);
        s += vals[i];
    }
#pragma unroll
    for (int off = 32; off >= 1; off >>= 1) s += __shfl_xor(s, off);
    if (lane == 0) reds[wave] = s;
    __syncthreads();
    s = reds[0] + reds[1] + reds[2] + reds[3];
    float inv = 1.0f / s;
#pragma unroll
    for (int i = 0; i < 8; ++i) row[tid + i * 256] = vals[i] * inv;
}

extern "C" void kernel_launch(void* const* d_in, const int* in_sizes, int n_in,
                              void* d_out, int out_size, void* d_ws, size_t ws_size,
                              hipStream_t stream) {
    const float* stat = (const float*)d_in[0];   // [64,2048,256]
    const float* dyn  = (const float*)d_in[1];   // [64,2048,256]
    const float* dec  = (const float*)d_in[2];   // [64,256]
    const float* v    = (const float*)d_in[3];   // [1,768]
    const float* W    = (const float*)d_in[4];   // [768,768]
    float* out = (float*)d_out;                  // [64,2048]

    short* wpk  = (short*)d_ws;                                   // 786432 B
    float* bias = (float*)((char*)d_ws + (size_t)H3_ * 512 * 2);  // 196608 B

    pack_w <<<(48 * 16 * 64 + 255) / 256, 256, 0, stream>>>(W, wpk);
    bias_k <<<(B_ * H3_ + 255) / 256, 256, 0, stream>>>(W, dec, bias);
    score_k<<<(B_ * S_) / MT, 512, 0, stream>>>(stat, dyn, wpk, bias, v, out);
    softmax_k<<<B_, 256, 0, stream>>>(out);
}

// Round 15
// 133.860 us; speedup vs baseline: 4.4113x; 1.1397x over previous
//
#include <hip/hip_runtime.h>
#include <hip/hip_bf16.h>

#define B_   64
#define S_   2048
#define H_   256
#define H3_  768
#define K_   512            // 2H (static+dynamic)
#define MT   64             // M tile (positions per workgroup)
#define RSTR 1040           // LDS row stride in bytes (65 x 16B): 2-way banks, imm-foldable

typedef __attribute__((ext_vector_type(8))) short  bf16x8;
typedef __attribute__((ext_vector_type(4))) float  f32x4;

__device__ __forceinline__ uint pkbf2(float a, float b) {
    float2 f = make_float2(a, b);
    __hip_bfloat162 h = __float22bfloat162_rn(f);   // v_cvt_pk_bf16_f32
    return *reinterpret_cast<uint*>(&h);
}

// ---------------- kernel 1: pack W[:, 0:512] to bf16 in FRAGMENT order.
// Layout: [ot(48)][ks(16)][lane(64)][j(8)]
//   o = ot*16 + (lane&15), k = ks*32 + (lane>>4)*8 + j
__global__ void pack_w(const float* __restrict__ W, short* __restrict__ wpk) {
    int t = blockIdx.x * 256 + threadIdx.x;       // over 48*16*64
    if (t >= 48 * 16 * 64) return;
    int lane = t & 63;
    int ks   = (t >> 6) & 15;
    int ot   = t >> 10;
    int o  = ot * 16 + (lane & 15);
    int kb = ks * 32 + (lane >> 4) * 8;
    const float* src = W + (size_t)o * H3_ + kb;
    float4 a = ((const float4*)src)[0];
    float4 b = ((const float4*)src)[1];
    uint4 pk;
    pk.x = pkbf2(a.x, a.y);
    pk.y = pkbf2(a.z, a.w);
    pk.z = pkbf2(b.x, b.y);
    pk.w = pkbf2(b.z, b.w);
    *(uint4*)(wpk + (size_t)t * 8) = pk;
}

// ---------------- kernel 2: bias[b,o] = sum_k W[o,512+k]*dec[b,k]; block 192: vsum
__global__ void bias_k(const float* __restrict__ W, const float* __restrict__ dec,
                       const float* __restrict__ v, float* __restrict__ bias,
                       float* __restrict__ vsum) {
    if (blockIdx.x == 192) {                      // reduce sum(v) with one wave
        if (threadIdx.x < 64) {
            float s = 0.f;
#pragma unroll
            for (int i = 0; i < 12; ++i) s += v[threadIdx.x + i * 64];
#pragma unroll
            for (int off = 32; off >= 1; off >>= 1) s += __shfl_xor(s, off);
            if (threadIdx.x == 0) vsum[0] = s;
        }
        return;
    }
    int idx = blockIdx.x * 256 + threadIdx.x;     // over 64*768
    int b = idx / H3_;
    int o = idx - b * H3_;
    const float4* wr = (const float4*)(W + (size_t)o * H3_ + 2 * H_);
    const float4* dv = (const float4*)(dec + (size_t)b * H_);
    float s = 0.f;
#pragma unroll 8
    for (int k = 0; k < H_ / 4; ++k) {
        float4 a = wr[k], d = dv[k];
        s += a.x * d.x + a.y * d.y + a.z * d.z + a.w * d.w;
    }
    bias[idx] = s;
}

// ---------------- kernel 3: fused score GEMM (R10 skeleton + 2-deep B pipeline)
// scores[pos] = vsum + sum_o (-2 v[o]) * rcp(exp2(C1*h[pos,o]) + 1)
//   where h = X·W^T + bias  (tanh identity), C1 = 2*log2(e)
__global__ __launch_bounds__(256, 2)
void score_k(const float* __restrict__ stat, const float* __restrict__ dyn,
             const short* __restrict__ wpk, const float* __restrict__ bias,
             const float* __restrict__ v, const float* __restrict__ vsum,
             float* __restrict__ scores) {
    __shared__ char  aT[MT * RSTR];          // 65 KB, pad-1040 layout
    __shared__ float sred[4][MT];            // 1 KB

    const int tid  = threadIdx.x;
    const int pos0 = blockIdx.x * MT;
    const int bidx = pos0 >> 11;             // /2048 ; tile never crosses b

    const int wave = tid >> 6;
    const int lane = tid & 63;
    const int lr = lane & 15;                // A: row-in-16 ; B/C: col-in-16
    const int lg = lane >> 4;                // k-group (8 elems each)

    const short* wbase = wpk + (size_t)lane * 8;   // + ot*8192 + ks*512

    // 2-deep B pipeline: preload pass-0 ks0/ks1 (latency hides under staging)
    bf16x8 bcur[4], bnx1[4];
#pragma unroll
    for (int ni = 0; ni < 4; ++ni) {
        const short* p = wbase + (size_t)(wave * 4 + ni) * 8192;
        bcur[ni] = *(const bf16x8*)(p);
        bnx1[ni] = *(const bf16x8*)(p + 512);
    }

    // ---- stage A: 64 rows x 512 k; 8 floats/unit (2x float4 -> 16B ds_write)
#pragma unroll
    for (int bat = 0; bat < 2; ++bat) {
        float4 f0[8], f1[8];
#pragma unroll
        for (int u = 0; u < 8; ++u) {
            int lin = (bat * 8 + u) * 256 + tid;
            int row = lin >> 6;              // 64 units per row
            int k   = (lin & 63) * 8;
            const float* src = (k < 256)
                ? (stat + (size_t)(pos0 + row) * H_ + k)
                : (dyn  + (size_t)(pos0 + row) * H_ + (k - 256));
            f0[u] = ((const float4*)src)[0];
            f1[u] = ((const float4*)src)[1];
        }
#pragma unroll
        for (int u = 0; u < 8; ++u) {
            int lin = (bat * 8 + u) * 256 + tid;
            int row = lin >> 6;
            int ux  = lin & 63;
            uint4 pk;
            pk.x = pkbf2(f0[u].x, f0[u].y);
            pk.y = pkbf2(f0[u].z, f0[u].w);
            pk.z = pkbf2(f1[u].x, f1[u].y);
            pk.w = pkbf2(f1[u].z, f1[u].w);
            *(uint4*)(aT + row * RSTR + ux * 16) = pk;
        }
    }
    __syncthreads();

    // single base address for A-fragment reads (imm offsets cover mi, ks window)
    const char* abase = aT + lr * RSTR + lg * 16;

    float sacc[4][4];
#pragma unroll
    for (int mi = 0; mi < 4; ++mi)
#pragma unroll
        for (int j = 0; j < 4; ++j) sacc[mi][j] = 0.f;

    const float C1 = 2.8853900817779268f;    // 2*log2(e)

    // 3 passes x (4 waves x 64 cols) = 768 cols
#pragma unroll 1
    for (int pass = 0; pass < 3; ++pass) {
        const int obase = pass * 256 + wave * 64;      // this wave's 64 cols

        float bv[4], vv2[4];
#pragma unroll
        for (int ni = 0; ni < 4; ++ni) {
            int o = obase + ni * 16 + lr;
            bv[ni]  = bias[bidx * H3_ + o];
            vv2[ni] = -2.0f * v[o];
        }

        f32x4 acc[4][4];                               // [mi][ni], init = bias
#pragma unroll
        for (int mi = 0; mi < 4; ++mi)
#pragma unroll
            for (int ni = 0; ni < 4; ++ni) {
                f32x4 a = {bv[ni], bv[ni], bv[ni], bv[ni]};
                acc[mi][ni] = a;
            }

        const short* wp  = wbase + (size_t)(pass * 16 + wave * 4) * 8192;
        // next pass's base (pass 2 wraps to pass 0: harmless dummy prefetch)
        const short* wpn = wbase + (size_t)(((pass + 1) % 3) * 16 + wave * 4) * 8192;

        // one ks-step: issue B for ks+2 (bptr), compute with bcur, rotate
        auto step = [&](const short* bptr, int ks) {
            bf16x8 bn2[4];
#pragma unroll
            for (int ni = 0; ni < 4; ++ni)
                bn2[ni] = *(const bf16x8*)(bptr + ni * 8192);
            bf16x8 afr[4];
#pragma unroll
            for (int mi = 0; mi < 4; ++mi)
                afr[mi] = *(const bf16x8*)(abase + mi * 16 * RSTR + ks * 64);
            __builtin_amdgcn_s_setprio(1);
#pragma unroll
            for (int mi = 0; mi < 4; ++mi)
#pragma unroll
                for (int ni = 0; ni < 4; ++ni)
                    acc[mi][ni] = __builtin_amdgcn_mfma_f32_16x16x32_bf16(
                        afr[mi], bcur[ni], acc[mi][ni], 0, 0, 0);
            __builtin_amdgcn_s_setprio(0);
#pragma unroll
            for (int ni = 0; ni < 4; ++ni) {
                bcur[ni] = bnx1[ni];
                bnx1[ni] = bn2[ni];
            }
        };

#pragma unroll 2
        for (int ks = 0; ks < 14; ++ks)
            step(wp + (ks + 2) * 512, ks);
        step(wpn, 14);                       // preloads next pass ks0
        step(wpn + 512, 15);                 // preloads next pass ks1

        // epilogue: sacc += (-2 v) * rcp(exp2(C1*h)+1)
#pragma unroll
        for (int ni = 0; ni < 4; ++ni)
#pragma unroll
            for (int mi = 0; mi < 4; ++mi)
#pragma unroll
                for (int j = 0; j < 4; ++j) {
                    float e = __builtin_amdgcn_exp2f(acc[mi][ni][j] * C1);
                    float r = __builtin_amdgcn_rcpf(e + 1.0f);
                    sacc[mi][j] = fmaf(vv2[ni], r, sacc[mi][j]);
                }
    }

    // reduce over the 16 column-lanes (lr); rows live at mi*16 + lg*4 + j
#pragma unroll
    for (int mi = 0; mi < 4; ++mi)
#pragma unroll
        for (int j = 0; j < 4; ++j) {
            float x = sacc[mi][j];
            x += __shfl_xor(x, 1);
            x += __shfl_xor(x, 2);
            x += __shfl_xor(x, 4);
            x += __shfl_xor(x, 8);
            sacc[mi][j] = x;
        }
    if (lr == 0) {
#pragma unroll
        for (int mi = 0; mi < 4; ++mi)
#pragma unroll
            for (int j = 0; j < 4; ++j)
                sred[wave][mi * 16 + lg * 4 + j] = sacc[mi][j];
    }
    __syncthreads();
    if (tid < MT) {
        float s = vsum[0] + sred[0][tid] + sred[1][tid] + sred[2][tid] + sred[3][tid];
        scores[pos0 + tid] = s;
    }
}

// ---------------- kernel 4: softmax over S=2048 per b, in place on d_out
__global__ void softmax_k(float* __restrict__ out) {
    const int b = blockIdx.x;
    float* row = out + (size_t)b * S_;
    const int tid  = threadIdx.x;          // 256
    const int wave = tid >> 6;
    const int lane = tid & 63;

    float vals[8];
    float m = -1e30f;
#pragma unroll
    for (int i = 0; i < 8; ++i) {
        vals[i] = row[tid + i * 256];
        m = fmaxf(m, vals[i]);
    }
#pragma unroll
    for (int off = 32; off >= 1; off >>= 1) m = fmaxf(m, __shfl_xor(m, off));
    __shared__ float redm[4];
    __shared__ float reds[4];
    if (lane == 0) redm[wave] = m;
    __syncthreads();
    m = fmaxf(fmaxf(redm[0], redm[1]), fmaxf(redm[2], redm[3]));

    float s = 0.f;
#pragma unroll
    for (int i = 0; i < 8; ++i) {
        vals[i] = __expf(vals[i] - m);
        s += vals[i];
    }
#pragma unroll
    for (int off = 32; off >= 1; off >>= 1) s += __shfl_xor(s, off);
    if (lane == 0) reds[wave] = s;
    __syncthreads();
    s = reds[0] + reds[1] + reds[2] + reds[3];
    float inv = 1.0f / s;
#pragma unroll
    for (int i = 0; i < 8; ++i) row[tid + i * 256] = vals[i] * inv;
}

extern "C" void kernel_launch(void* const* d_in, const int* in_sizes, int n_in,
                              void* d_out, int out_size, void* d_ws, size_t ws_size,
                              hipStream_t stream) {
    const float* stat = (const float*)d_in[0];   // [64,2048,256]
    const float* dyn  = (const float*)d_in[1];   // [64,2048,256]
    const float* dec  = (const float*)d_in[2];   // [64,256]
    const float* v    = (const float*)d_in[3];   // [1,768]
    const float* W    = (const float*)d_in[4];   // [768,768]
    float* out = (float*)d_out;                  // [64,2048]

    short* wpk  = (short*)d_ws;                                 // 786432 B
    float* bias = (float*)((char*)d_ws + (size_t)H3_ * K_ * 2); // 196608 B
    float* vsum = bias + B_ * H3_;                              // 4 B

    pack_w <<<(48 * 16 * 64 + 255) / 256, 256, 0, stream>>>(W, wpk);
    bias_k <<<193, 256, 0, stream>>>(W, dec, v, bias, vsum);
    score_k<<<(B_ * S_) / MT, 256, 0, stream>>>(stat, dyn, wpk, bias, v, vsum, out);
    softmax_k<<<B_, 256, 0, stream>>>(out);
}